// Round 3
// baseline (224.080 us; speedup 1.0000x reference)
//
#include <hip/hip_runtime.h>

#define NODES 128
#define NFEAT 256
#define BATCH 512
#define KTOT  (NODES * NFEAT)   // 32768, stage-3 K
#define SPLIT 32                // stage-3 split-K factor
#define KCH   (KTOT / SPLIT)    // 1024 per chunk

typedef __bf16 bf16_t;
typedef bf16_t bf16x8 __attribute__((ext_vector_type(8)));
typedef float  f32x4  __attribute__((ext_vector_type(4)));

#define BK   32
#define LDK  40      // padded bf16 LDS row (k_out A): 80B rows
#define LDM  136     // Sb row stride (bf16): 272B rows -> 4-bank row rotation
#define TILE 128

__device__ __forceinline__ bf16x8 cvt8(const float4 a, const float4 b) {
    bf16x8 t;
    t[0] = (bf16_t)a.x; t[1] = (bf16_t)a.y; t[2] = (bf16_t)a.z; t[3] = (bf16_t)a.w;
    t[4] = (bf16_t)b.x; t[5] = (bf16_t)b.y; t[6] = (bf16_t)b.z; t[7] = (bf16_t)b.w;
    return t;
}

// async global->LDS: one 16B dwordx4 per lane, LDS dest = wave-uniform base + lane*16
__device__ __forceinline__ void gload16(const float* g, float* l) {
    __builtin_amdgcn_global_load_lds(
        (const __attribute__((address_space(1))) void*)g,
        (__attribute__((address_space(3))) void*)l, 16, 0, 0);
}

// Async-stage a 128x32 fp32 tile into flat LDS [128][32] (lane-linear, NO padding).
// Column-chunk XOR swizzle applied to the GLOBAL source: LDS[r][c] = global[r][c^(r&7)]
// (chunks are 16B = 4 floats; same cache lines touched, so global stays coalesced).
__device__ __forceinline__ void stage_async(const float* __restrict__ src, int srcld,
                                            int k0, float* __restrict__ lds, int tid) {
#pragma unroll
    for (int i = 0; i < 4; i++) {
        int f = tid + i * 256;            // 0..1023
        int r = f >> 3, c = f & 7;        // row, 16B chunk
        const float* g = src + (size_t)r * srcld + k0 + ((c ^ (r & 7)) << 2);
        gload16(g, lds + ((f & ~63) << 2));   // wave-uniform base (floats)
    }
}

// Read one A/B fragment (row R, k-chunk q*8..q*8+7) from a swizzled fp32 tile, cvt to bf16.
__device__ __forceinline__ bf16x8 frag_f32(const float* __restrict__ lds, int R, int q) {
    const int s = R & 7;
    const float4 u0 = *(const float4*)(lds + R * 32 + (((2 * q)     ^ s) << 2));
    const float4 u1 = *(const float4*)(lds + R * 32 + (((2 * q + 1) ^ s) << 2));
    return cvt8(u0, u1);
}

// ---- pre-transpose gcn_w[k][g] -> wT[g][k] bf16 ----
__global__ __launch_bounds__(256)
void k_wt(const float* __restrict__ w, bf16_t* __restrict__ wT) {
    const int g0 = blockIdx.x * 4;
    const int k  = threadIdx.x;
    const float4 v = *(const float4*)(w + (size_t)k * NFEAT + g0);
    wT[(size_t)(g0 + 0) * NFEAT + k] = (bf16_t)v.x;
    wT[(size_t)(g0 + 1) * NFEAT + k] = (bf16_t)v.y;
    wT[(size_t)(g0 + 2) * NFEAT + k] = (bf16_t)v.z;
    wT[(size_t)(g0 + 3) * NFEAT + k] = (bf16_t)v.w;
}

// ---- fused stages 1+2, async double-buffered ----
__global__ __launch_bounds__(256, 2)
void k_fused12(const float* __restrict__ x, const float* __restrict__ adj,
               const bf16_t* __restrict__ wT, const float* __restrict__ gcn_b,
               bf16_t* __restrict__ mid) {
    __shared__ __align__(16) float  Axf[2][TILE * 32];   // 32 KB: async fp32 tiles
    __shared__ __align__(16) bf16_t Sb[TILE * LDM];      // 34 KB: S[g][m]
    const int n0  = blockIdx.x * TILE;   // g-tile (0 or 128)
    const int b   = blockIdx.y;
    const int tid = threadIdx.x;
    const int lane = tid & 63, w = tid >> 6, wm = w & 1, wn = w >> 1;
    const int l15 = lane & 15, q = lane >> 4;
    const float* xb   = x   + (size_t)b * NODES * NFEAT;
    const float* adjb = adj + (size_t)b * NODES * NODES;

    // per-wave wT row pointers (B-frag source, direct from global/L2)
    const bf16_t* wrow[4];
#pragma unroll
    for (int j = 0; j < 4; j++)
        wrow[j] = wT + (size_t)(n0 + wn * 64 + j * 16 + l15) * NFEAT + q * 8;

    // ---- stage 1: S = x[b] @ W  (K = 256) ----
    f32x4 acc[4][4] = {};
    stage_async(xb, NFEAT, 0, Axf[0], tid);
    bf16x8 bcur[4], bnxt[4];
#pragma unroll
    for (int j = 0; j < 4; j++) bcur[j] = *(const bf16x8*)(wrow[j]);
    __syncthreads();
    int p = 0;
    for (int k0 = 0; k0 < NFEAT; k0 += BK) {
        const int kn = k0 + BK;
        const float* cur = Axf[p];
        float* nxt = Axf[p ^ 1];
        if (kn < NFEAT) stage_async(xb, NFEAT, kn, nxt, tid);
        const int knc = (kn < NFEAT) ? kn : 0;
#pragma unroll
        for (int j = 0; j < 4; j++) bnxt[j] = *(const bf16x8*)(wrow[j] + knc);
        bf16x8 a[4];
#pragma unroll
        for (int i = 0; i < 4; i++) a[i] = frag_f32(cur, wm * 64 + i * 16 + l15, q);
#pragma unroll
        for (int i = 0; i < 4; i++)
#pragma unroll
            for (int j = 0; j < 4; j++)
                acc[i][j] = __builtin_amdgcn_mfma_f32_16x16x32_bf16(a[i], bcur[j], acc[i][j], 0, 0, 0);
        __syncthreads();   // drains async loads into nxt; all waves done reading cur
#pragma unroll
        for (int j = 0; j < 4; j++) bcur[j] = bnxt[j];
        p ^= 1;
    }

    // S -> Sb[g][m] bf16 (one-time)
#pragma unroll
    for (int i = 0; i < 4; i++)
#pragma unroll
        for (int j = 0; j < 4; j++)
#pragma unroll
            for (int r = 0; r < 4; r++) {
                int m = wm * 64 + i * 16 + q * 4 + r;
                int g = wn * 64 + j * 16 + l15;
                Sb[g * LDM + m] = (bf16_t)acc[i][j][r];
            }
    // ---- stage 2: mid = adj[b] @ S  (K = 128) ----
    stage_async(adjb, NODES, 0, Axf[0], tid);
    __syncthreads();   // Sb visible + adj tile 0 landed
    f32x4 acc2[4][4] = {};
    p = 0;
    for (int k0 = 0; k0 < NODES; k0 += BK) {
        const int kn = k0 + BK;
        const float* cur = Axf[p];
        float* nxt = Axf[p ^ 1];
        if (kn < NODES) stage_async(adjb, NODES, kn, nxt, tid);
        bf16x8 a[4], bb[4];
#pragma unroll
        for (int i = 0; i < 4; i++) a[i] = frag_f32(cur, wm * 64 + i * 16 + l15, q);
#pragma unroll
        for (int j = 0; j < 4; j++)
            bb[j] = *(const bf16x8*)(Sb + (wn * 64 + j * 16 + l15) * LDM + k0 + q * 8);
#pragma unroll
        for (int i = 0; i < 4; i++)
#pragma unroll
            for (int j = 0; j < 4; j++)
                acc2[i][j] = __builtin_amdgcn_mfma_f32_16x16x32_bf16(a[i], bb[j], acc2[i][j], 0, 0, 0);
        __syncthreads();
        p ^= 1;
    }
    // epilogue: + gcn_b -> mid[b][node][g]
    bf16_t* outb = mid + (size_t)b * NODES * NFEAT;
#pragma unroll
    for (int j = 0; j < 4; j++) {
        int g = n0 + wn * 64 + j * 16 + l15;
        float bias = gcn_b[g];
#pragma unroll
        for (int i = 0; i < 4; i++)
#pragma unroll
            for (int r = 0; r < 4; r++) {
                int node = wm * 64 + i * 16 + q * 4 + r;
                outb[(size_t)node * NFEAT + g] = (bf16_t)(acc2[i][j][r] + bias);
            }
    }
}

// ---- stage 3: split-K, async-dbuf fc_w staging ----
__global__ __launch_bounds__(256, 2)
void k_out(const bf16_t* __restrict__ flat, const float* __restrict__ fcw,
           float* __restrict__ part) {
    __shared__ __align__(16) bf16_t As2[2][TILE * LDK];  // 20 KB: flat tiles (padded)
    __shared__ __align__(16) float  Bsf[2][TILE * 32];   // 32 KB: async fcw fp32 tiles
    const int m0 = blockIdx.x * TILE;
    const int n0 = blockIdx.y * TILE;
    const int kb = blockIdx.z * KCH, kend = kb + KCH;
    const int tid = threadIdx.x;
    const int lane = tid & 63, w = tid >> 6, wm = w & 1, wn = w >> 1;
    const int l15 = lane & 15, q = lane >> 4;
    f32x4 acc[4][4] = {};
    const float* fb = fcw + (size_t)n0 * KTOT;

    // prologue: A(kb) via regs -> LDS, B(kb) async
    const int ar = tid >> 2, ac = tid & 3;   // thread stages rows ar, ar+64 (c=ac)
    bf16x8 a0 = *(const bf16x8*)(flat + (size_t)(m0 + ar) * KTOT + kb + ac * 8);
    bf16x8 a1 = *(const bf16x8*)(flat + (size_t)(m0 + 64 + ar) * KTOT + kb + ac * 8);
    stage_async(fb, KTOT, kb, Bsf[0], tid);
    *(bf16x8*)(As2[0] + ar * LDK + ac * 8) = a0;
    *(bf16x8*)(As2[0] + (64 + ar) * LDK + ac * 8) = a1;
    __syncthreads();
    int p = 0;
    for (int k0 = kb; k0 < kend; k0 += BK) {
        const int kn = k0 + BK;
        const bool in = kn < kend;
        const int knc = in ? kn : kb;
        if (in) stage_async(fb, KTOT, kn, Bsf[p ^ 1], tid);
        bf16x8 an0 = *(const bf16x8*)(flat + (size_t)(m0 + ar) * KTOT + knc + ac * 8);
        bf16x8 an1 = *(const bf16x8*)(flat + (size_t)(m0 + 64 + ar) * KTOT + knc + ac * 8);
        bf16x8 a[4], bbf[4];
#pragma unroll
        for (int i = 0; i < 4; i++)
            a[i] = *(const bf16x8*)(As2[p] + (wm * 64 + i * 16 + l15) * LDK + q * 8);
#pragma unroll
        for (int j = 0; j < 4; j++) bbf[j] = frag_f32(Bsf[p], wn * 64 + j * 16 + l15, q);
#pragma unroll
        for (int i = 0; i < 4; i++)
#pragma unroll
            for (int j = 0; j < 4; j++)
                acc[i][j] = __builtin_amdgcn_mfma_f32_16x16x32_bf16(a[i], bbf[j], acc[i][j], 0, 0, 0);
        if (in) {
            *(bf16x8*)(As2[p ^ 1] + ar * LDK + ac * 8) = an0;
            *(bf16x8*)(As2[p ^ 1] + (64 + ar) * LDK + ac * 8) = an1;
        }
        __syncthreads();
        p ^= 1;
    }
    float* pb = part + (size_t)blockIdx.z * BATCH * NFEAT;
#pragma unroll
    for (int i = 0; i < 4; i++)
#pragma unroll
        for (int j = 0; j < 4; j++)
#pragma unroll
            for (int r = 0; r < 4; r++) {
                int bt = m0 + wm * 64 + i * 16 + q * 4 + r;
                int o  = n0 + wn * 64 + j * 16 + l15;
                pb[(size_t)bt * NFEAT + o] = acc[i][j][r];
            }
}

// ---- stage 4: reduce partials + fc_b -> slots 0,2; x[:,0,:] -> slot 1 ----
__global__ __launch_bounds__(256)
void k_reduce(const float* __restrict__ part, const float* __restrict__ fc_b,
              const float* __restrict__ x, float* __restrict__ out) {
    const int g = blockIdx.x * 256 + threadIdx.x;
    const int o = g & (NFEAT - 1), b = g >> 8;
    float s = fc_b[o];
#pragma unroll
    for (int i = 0; i < SPLIT; i++)
        s += part[(size_t)i * BATCH * NFEAT + g];
    out[g] = s;
    out[BATCH * NFEAT + g] = x[(size_t)b * NODES * NFEAT + o];
    out[2 * BATCH * NFEAT + g] = s;
}

extern "C" void kernel_launch(void* const* d_in, const int* in_sizes, int n_in,
                              void* d_out, int out_size, void* d_ws, size_t ws_size,
                              hipStream_t stream) {
    const float* x     = (const float*)d_in[0];
    const float* adj   = (const float*)d_in[1];
    const float* gcn_w = (const float*)d_in[2];
    const float* gcn_b = (const float*)d_in[3];
    const float* fc_w  = (const float*)d_in[4];
    const float* fc_b  = (const float*)d_in[5];
    float* out = (float*)d_out;

    // ws: wT [0,128KB) | mid 33.5MB | part 16.8MB  (~50.4 MB total)
    bf16_t* wT   = (bf16_t*)d_ws;
    bf16_t* mid  = (bf16_t*)((char*)d_ws + 131072);
    float*  part = (float*)((char*)d_ws + 131072 + (size_t)BATCH * NODES * NFEAT * 2);

    k_wt     <<<dim3(64), dim3(256), 0, stream>>>(gcn_w, wT);
    k_fused12<<<dim3(2, BATCH), dim3(256), 0, stream>>>(x, adj, wT, gcn_b, mid);
    k_out    <<<dim3(4, 2, SPLIT), dim3(256), 0, stream>>>(mid, fc_w, part);
    k_reduce <<<dim3(BATCH), dim3(256), 0, stream>>>(part, fc_b, x, out);
}

// Round 4
// 209.714 us; speedup vs baseline: 1.0685x; 1.0685x over previous
//
#include <hip/hip_runtime.h>

#define NODES 128
#define NFEAT 256
#define BATCH 512
#define KTOT  (NODES * NFEAT)   // 32768, stage-3 K
#define SPLIT 64                // stage-3 split-K factor
#define KCH   (KTOT / SPLIT)    // 512 per chunk

typedef __bf16 bf16_t;
typedef bf16_t bf16x8 __attribute__((ext_vector_type(8)));
typedef float  f32x4  __attribute__((ext_vector_type(4)));

#define BK   32
#define LDK  40      // padded bf16 LDS row: 80B rows, 2-way bank alias (free)
#define LDM  136     // Sb row stride (bf16)
#define TILE 128

__device__ __forceinline__ bf16x8 cvt8(const float4 a, const float4 b) {
    bf16x8 t;
    t[0] = (bf16_t)a.x; t[1] = (bf16_t)a.y; t[2] = (bf16_t)a.z; t[3] = (bf16_t)a.w;
    t[4] = (bf16_t)b.x; t[5] = (bf16_t)b.y; t[6] = (bf16_t)b.z; t[7] = (bf16_t)b.w;
    return t;
}

// ---- fp32 128x32 tile: reg-load / LDS-store halves (2-barrier pipeline) ----
// thread f (0..511 over 2 steps): row r=f>>2, 8-col chunk c=f&3.
struct XT { float4 v[4]; };
__device__ __forceinline__ void xload(const float* __restrict__ src, int ld, int k0,
                                      int tid, XT& t) {
#pragma unroll
    for (int i = 0; i < 2; i++) {
        int f = tid + i * 256, r = f >> 2, c = f & 3;
        t.v[2 * i]     = *(const float4*)(src + (size_t)r * ld + k0 + c * 8);
        t.v[2 * i + 1] = *(const float4*)(src + (size_t)r * ld + k0 + c * 8 + 4);
    }
}
__device__ __forceinline__ void xstore(bf16_t* __restrict__ dst, int tid, const XT& t) {
#pragma unroll
    for (int i = 0; i < 2; i++) {
        int f = tid + i * 256, r = f >> 2, c = f & 3;
        *(bf16x8*)(dst + r * LDK + c * 8) = cvt8(t.v[2 * i], t.v[2 * i + 1]);
    }
}

// ---- bf16 128x32 tile (K-contiguous source): reg-load / LDS-store ----
struct AT { bf16x8 v[2]; };
__device__ __forceinline__ void aload(const bf16_t* __restrict__ src, int ld, int k0,
                                      int tid, AT& t) {
#pragma unroll
    for (int i = 0; i < 2; i++) {
        int f = tid + i * 256, r = f >> 2, c = f & 3;
        t.v[i] = *(const bf16x8*)(src + (size_t)r * ld + k0 + c * 8);
    }
}
__device__ __forceinline__ void astore(bf16_t* __restrict__ dst, int tid, const AT& t) {
#pragma unroll
    for (int i = 0; i < 2; i++) {
        int f = tid + i * 256, r = f >> 2, c = f & 3;
        *(bf16x8*)(dst + r * LDK + c * 8) = t.v[i];
    }
}

// ---- pre-transpose gcn_w[k][g] -> wT[g][k] bf16 ----
__global__ __launch_bounds__(256)
void k_wt(const float* __restrict__ w, bf16_t* __restrict__ wT) {
    const int g0 = blockIdx.x * 4;
    const int k  = threadIdx.x;
    const float4 v = *(const float4*)(w + (size_t)k * NFEAT + g0);
    wT[(size_t)(g0 + 0) * NFEAT + k] = (bf16_t)v.x;
    wT[(size_t)(g0 + 1) * NFEAT + k] = (bf16_t)v.y;
    wT[(size_t)(g0 + 2) * NFEAT + k] = (bf16_t)v.z;
    wT[(size_t)(g0 + 3) * NFEAT + k] = (bf16_t)v.w;
}

// ---- fused stages 1+2: 2-barrier reg-prefetch loops, 3 blocks/CU ----
__global__ __launch_bounds__(256, 3)
void k_fused12(const float* __restrict__ x, const float* __restrict__ adj,
               const bf16_t* __restrict__ wT, const float* __restrict__ gcn_b,
               bf16_t* __restrict__ mid) {
    __shared__ __align__(16) bf16_t As[TILE * LDK];   // 10.2 KB
    __shared__ __align__(16) bf16_t Sb[TILE * LDM];   // 34.8 KB
    const int n0  = blockIdx.x * TILE;   // g-tile (0 or 128)
    const int b   = blockIdx.y;
    const int tid = threadIdx.x;
    const int lane = tid & 63, w = tid >> 6, wm = w & 1, wn = w >> 1;
    const int l15 = lane & 15, q = lane >> 4;
    const float* xb   = x   + (size_t)b * NODES * NFEAT;
    const float* adjb = adj + (size_t)b * NODES * NODES;

    const bf16_t* wrow[4];
#pragma unroll
    for (int j = 0; j < 4; j++)
        wrow[j] = wT + (size_t)(n0 + wn * 64 + j * 16 + l15) * NFEAT + q * 8;

    // ---- stage 1: S = x[b] @ W  (K=256, 8 iters) ----
    f32x4 acc[4][4] = {};
    {
        XT xt; xload(xb, NFEAT, 0, tid, xt);
        bf16x8 bcur[4], bnxt[4];
#pragma unroll
        for (int j = 0; j < 4; j++) bcur[j] = *(const bf16x8*)(wrow[j]);
        xstore(As, tid, xt);
        __syncthreads();
        for (int k0 = 0; k0 < NFEAT; k0 += BK) {
            const int kn = k0 + BK;
            const bool in = kn < NFEAT;
            XT xn;
            if (in) xload(xb, NFEAT, kn, tid, xn);          // HBM loads in flight
            const int knc = in ? kn : 0;
#pragma unroll
            for (int j = 0; j < 4; j++) bnxt[j] = *(const bf16x8*)(wrow[j] + knc); // L2
            bf16x8 a[4];
#pragma unroll
            for (int i = 0; i < 4; i++)
                a[i] = *(const bf16x8*)(As + (wm * 64 + i * 16 + l15) * LDK + q * 8);
#pragma unroll
            for (int i = 0; i < 4; i++)
#pragma unroll
                for (int j = 0; j < 4; j++)
                    acc[i][j] = __builtin_amdgcn_mfma_f32_16x16x32_bf16(a[i], bcur[j], acc[i][j], 0, 0, 0);
            __syncthreads();            // everyone done reading As(k)
            if (in) xstore(As, tid, xn);
#pragma unroll
            for (int j = 0; j < 4; j++) bcur[j] = bnxt[j];
            __syncthreads();            // As(k+1) ready
        }
    }

    // stage-2 tile-0 loads in flight while we write Sb
    XT at; xload(adjb, NODES, 0, tid, at);
    // S -> Sb[g][m] bf16
#pragma unroll
    for (int i = 0; i < 4; i++)
#pragma unroll
        for (int j = 0; j < 4; j++)
#pragma unroll
            for (int r = 0; r < 4; r++) {
                int m = wm * 64 + i * 16 + q * 4 + r;
                int g = wn * 64 + j * 16 + l15;
                Sb[g * LDM + m] = (bf16_t)acc[i][j][r];
            }
    __syncthreads();                    // As free (stage-1 reads done) + Sb visible
    xstore(As, tid, at);
    __syncthreads();

    // ---- stage 2: mid = adj[b] @ S  (K=128, 4 iters) ----
    f32x4 acc2[4][4] = {};
    for (int k0 = 0; k0 < NODES; k0 += BK) {
        const int kn = k0 + BK;
        const bool in = kn < NODES;
        XT xn;
        if (in) xload(adjb, NODES, kn, tid, xn);
        bf16x8 a[4], bb[4];
#pragma unroll
        for (int i = 0; i < 4; i++)
            a[i] = *(const bf16x8*)(As + (wm * 64 + i * 16 + l15) * LDK + q * 8);
#pragma unroll
        for (int j = 0; j < 4; j++)
            bb[j] = *(const bf16x8*)(Sb + (wn * 64 + j * 16 + l15) * LDM + k0 + q * 8);
#pragma unroll
        for (int i = 0; i < 4; i++)
#pragma unroll
            for (int j = 0; j < 4; j++)
                acc2[i][j] = __builtin_amdgcn_mfma_f32_16x16x32_bf16(a[i], bb[j], acc2[i][j], 0, 0, 0);
        __syncthreads();
        if (in) xstore(As, tid, xn);
        __syncthreads();
    }
    // epilogue: + gcn_b -> mid[b][node][g]
    bf16_t* outb = mid + (size_t)b * NODES * NFEAT;
#pragma unroll
    for (int j = 0; j < 4; j++) {
        int g = n0 + wn * 64 + j * 16 + l15;
        float bias = gcn_b[g];
#pragma unroll
        for (int i = 0; i < 4; i++)
#pragma unroll
            for (int r = 0; r < 4; r++) {
                int node = wm * 64 + i * 16 + q * 4 + r;
                outb[(size_t)node * NFEAT + g] = (bf16_t)(acc2[i][j][r] + bias);
            }
    }
}

// ---- stage 3: split-K=64, 2-barrier reg-prefetch; bf16 partials ----
__global__ __launch_bounds__(256, 2)
void k_out(const bf16_t* __restrict__ flat, const float* __restrict__ fcw,
           bf16_t* __restrict__ part) {
    __shared__ __align__(16) bf16_t As[TILE * LDK];   // 10.2 KB
    __shared__ __align__(16) bf16_t Bs[TILE * LDK];   // 10.2 KB
    const int m0 = blockIdx.x * TILE;
    const int n0 = blockIdx.y * TILE;
    const int kb = blockIdx.z * KCH, kend = kb + KCH;
    const int tid = threadIdx.x;
    const int lane = tid & 63, w = tid >> 6, wm = w & 1, wn = w >> 1;
    const int l15 = lane & 15, q = lane >> 4;
    f32x4 acc[4][4] = {};
    const bf16_t* fa = flat + (size_t)m0 * KTOT;
    const float*  fb = fcw + (size_t)n0 * KTOT;

    AT a0; aload(fa, KTOT, kb, tid, a0);
    XT b0; xload(fb, KTOT, kb, tid, b0);
    astore(As, tid, a0);
    xstore(Bs, tid, b0);
    __syncthreads();
    for (int k0 = kb; k0 < kend; k0 += BK) {
        const int kn = k0 + BK;
        const bool in = kn < kend;
        AT an; XT bn;
        if (in) { aload(fa, KTOT, kn, tid, an); xload(fb, KTOT, kn, tid, bn); }
        bf16x8 a[4], bbf[4];
#pragma unroll
        for (int i = 0; i < 4; i++)
            a[i] = *(const bf16x8*)(As + (wm * 64 + i * 16 + l15) * LDK + q * 8);
#pragma unroll
        for (int j = 0; j < 4; j++)
            bbf[j] = *(const bf16x8*)(Bs + (wn * 64 + j * 16 + l15) * LDK + q * 8);
#pragma unroll
        for (int i = 0; i < 4; i++)
#pragma unroll
            for (int j = 0; j < 4; j++)
                acc[i][j] = __builtin_amdgcn_mfma_f32_16x16x32_bf16(a[i], bbf[j], acc[i][j], 0, 0, 0);
        __syncthreads();
        if (in) { astore(As, tid, an); xstore(Bs, tid, bn); }
        __syncthreads();
    }
    bf16_t* pb = part + (size_t)blockIdx.z * BATCH * NFEAT;
#pragma unroll
    for (int i = 0; i < 4; i++)
#pragma unroll
        for (int j = 0; j < 4; j++)
#pragma unroll
            for (int r = 0; r < 4; r++) {
                int bt = m0 + wm * 64 + i * 16 + q * 4 + r;
                int o  = n0 + wn * 64 + j * 16 + l15;
                pb[(size_t)bt * NFEAT + o] = (bf16_t)acc[i][j][r];
            }
}

// ---- stage 4: reduce bf16 partials + fc_b -> slots 0,2; x[:,0,:] -> slot 1 ----
__global__ __launch_bounds__(256)
void k_reduce(const bf16_t* __restrict__ part, const float* __restrict__ fc_b,
              const float* __restrict__ x, float* __restrict__ out) {
    const int g = blockIdx.x * 256 + threadIdx.x;
    const int o = g & (NFEAT - 1), b = g >> 8;
    float s = fc_b[o];
#pragma unroll
    for (int i = 0; i < SPLIT; i++)
        s += (float)part[(size_t)i * BATCH * NFEAT + g];
    out[g] = s;
    out[BATCH * NFEAT + g] = x[(size_t)b * NODES * NFEAT + o];
    out[2 * BATCH * NFEAT + g] = s;
}

extern "C" void kernel_launch(void* const* d_in, const int* in_sizes, int n_in,
                              void* d_out, int out_size, void* d_ws, size_t ws_size,
                              hipStream_t stream) {
    const float* x     = (const float*)d_in[0];
    const float* adj   = (const float*)d_in[1];
    const float* gcn_w = (const float*)d_in[2];
    const float* gcn_b = (const float*)d_in[3];
    const float* fc_w  = (const float*)d_in[4];
    const float* fc_b  = (const float*)d_in[5];
    float* out = (float*)d_out;

    // ws: wT 128KB | mid 33.5MB | part (bf16) 16.8MB  => ~50.5 MB
    bf16_t* wT   = (bf16_t*)d_ws;
    bf16_t* mid  = (bf16_t*)((char*)d_ws + 131072);
    bf16_t* part = (bf16_t*)((char*)d_ws + 131072 + (size_t)BATCH * NODES * NFEAT * 2);

    k_wt     <<<dim3(64), dim3(256), 0, stream>>>(gcn_w, wT);
    k_fused12<<<dim3(2, BATCH), dim3(256), 0, stream>>>(x, adj, wT, gcn_b, mid);
    k_out    <<<dim3(4, 2, SPLIT), dim3(256), 0, stream>>>(mid, fc_w, part);
    k_reduce <<<dim3(BATCH), dim3(256), 0, stream>>>(part, fc_b, x, out);
}